// Round 1
// baseline (97.461 us; speedup 1.0000x reference)
//
#include <hip/hip_runtime.h>
#include <hip/hip_bf16.h>

#define HIDDEN 1024
#define HEADS  2560
#define BM 128
#define BN 128
#define BK 32
#define LDK 40   // padded K stride (bf16 elems): row stride 80B -> 8-bank spread, ~conflict-free

typedef float  f32x4  __attribute__((ext_vector_type(4)));
typedef __bf16 bf16x8 __attribute__((ext_vector_type(8)));
typedef __bf16 bf16x4 __attribute__((ext_vector_type(4)));

__global__ __launch_bounds__(256)
void lch_gemm(const float* __restrict__ x, const float* __restrict__ W,
              const float* __restrict__ b, float* __restrict__ out)
{
    __shared__ __bf16 As[BM][LDK];   // x tile, [m][k]
    __shared__ __bf16 Bs[BN][LDK];   // W tile transposed, [n][k]

    const int t   = threadIdx.x;
    const int bm0 = blockIdx.x * BM;
    const int bn0 = blockIdx.y * BN;

    const int lane = t & 63;
    const int wid  = t >> 6;
    const int wr   = wid >> 1;   // 0..1
    const int wc   = wid & 1;    // 0..1
    const int lhi  = lane >> 4;  // 0..3
    const int llo  = lane & 15;  // 0..15

    f32x4 acc[4][4];
    #pragma unroll
    for (int i = 0; i < 4; ++i)
        #pragma unroll
        for (int j = 0; j < 4; ++j)
            acc[i][j] = f32x4{0.f, 0.f, 0.f, 0.f};

    // B staging coords: thread covers one n-column, 16 k-values
    const int bn_col  = t & 127;        // 0..127
    const int bk_base = (t >> 7) * 16;  // 0 or 16

    for (int k0 = 0; k0 < HIDDEN; k0 += BK) {
        // ---- stage A: x[bm0..+128][k0..+32], f32 -> bf16 ----
        #pragma unroll
        for (int i = 0; i < 4; ++i) {
            const int f   = t + i * 256;     // float4 index, 0..1023
            const int row = f >> 3;          // 0..127
            const int c4  = (f & 7) * 4;     // 0..28
            const float4 v = *reinterpret_cast<const float4*>(
                x + (size_t)(bm0 + row) * HIDDEN + k0 + c4);
            bf16x4 h;
            h[0] = (__bf16)v.x; h[1] = (__bf16)v.y;
            h[2] = (__bf16)v.z; h[3] = (__bf16)v.w;
            *reinterpret_cast<bf16x4*>(&As[row][c4]) = h;
        }
        // ---- stage B transposed: Bs[n][k] = W[k0+k][bn0+n] ----
        {
            const float* wp = W + (size_t)(k0 + bk_base) * HEADS + bn0 + bn_col;
            bf16x8 h0, h1;
            #pragma unroll
            for (int i = 0; i < 8; ++i) h0[i] = (__bf16)wp[(size_t)i * HEADS];
            #pragma unroll
            for (int i = 0; i < 8; ++i) h1[i] = (__bf16)wp[(size_t)(i + 8) * HEADS];
            *reinterpret_cast<bf16x8*>(&Bs[bn_col][bk_base])     = h0;
            *reinterpret_cast<bf16x8*>(&Bs[bn_col][bk_base + 8]) = h1;
        }
        __syncthreads();

        // ---- fragments + MFMA ----
        bf16x8 af[4], bfr[4];
        #pragma unroll
        for (int i = 0; i < 4; ++i)
            af[i] = *reinterpret_cast<const bf16x8*>(&As[wr * 64 + i * 16 + llo][lhi * 8]);
        #pragma unroll
        for (int j = 0; j < 4; ++j)
            bfr[j] = *reinterpret_cast<const bf16x8*>(&Bs[wc * 64 + j * 16 + llo][lhi * 8]);
        #pragma unroll
        for (int i = 0; i < 4; ++i)
            #pragma unroll
            for (int j = 0; j < 4; ++j)
                acc[i][j] = __builtin_amdgcn_mfma_f32_16x16x32_bf16(
                    af[i], bfr[j], acc[i][j], 0, 0, 0);
        __syncthreads();
    }

    // ---- epilogue: bias + sigmoid + store f32 ----
    // C/D layout (m89-verified): col = lane&15, row = (lane>>4)*4 + reg
    #pragma unroll
    for (int j = 0; j < 4; ++j) {
        const int col  = bn0 + wc * 64 + j * 16 + llo;
        const float bias = b[col];
        #pragma unroll
        for (int i = 0; i < 4; ++i) {
            const int row0 = bm0 + wr * 64 + i * 16 + lhi * 4;
            #pragma unroll
            for (int r = 0; r < 4; ++r) {
                const float z = acc[i][j][r] + bias;
                out[(size_t)(row0 + r) * HEADS + col] = 1.0f / (1.0f + __expf(-z));
            }
        }
    }
}

extern "C" void kernel_launch(void* const* d_in, const int* in_sizes, int n_in,
                              void* d_out, int out_size, void* d_ws, size_t ws_size,
                              hipStream_t stream) {
    const float* x = (const float*)d_in[0];
    const float* W = (const float*)d_in[1];
    const float* b = (const float*)d_in[2];
    float* out     = (float*)d_out;

    const int M = in_sizes[0] / HIDDEN;   // 8192
    dim3 grid(M / BM, HEADS / BN);        // (64, 20)
    lch_gemm<<<grid, dim3(256), 0, stream>>>(x, W, b, out);
}

// Round 2
// 96.946 us; speedup vs baseline: 1.0053x; 1.0053x over previous
//
#include <hip/hip_runtime.h>
#include <hip/hip_bf16.h>

#define HIDDEN 1024
#define HEADS  2560

typedef float  f32x4  __attribute__((ext_vector_type(4)));
typedef __bf16 bf16x8 __attribute__((ext_vector_type(8)));
typedef __bf16 bf16x4 __attribute__((ext_vector_type(4)));

// ---------------------------------------------------------------------------
// Pass 1a: x f32 -> bf16, elementwise, [M][K] layout preserved.
// ---------------------------------------------------------------------------
__global__ __launch_bounds__(256)
void cvt_x(const float* __restrict__ x, __bf16* __restrict__ xc, int n8)
{
    // n8 = total elems / 8
    int idx = blockIdx.x * blockDim.x + threadIdx.x;
    int stride = gridDim.x * blockDim.x;
    for (int i = idx; i < n8; i += stride) {
        const float4 a = *reinterpret_cast<const float4*>(x + (size_t)i * 8);
        const float4 b = *reinterpret_cast<const float4*>(x + (size_t)i * 8 + 4);
        bf16x8 h;
        h[0] = (__bf16)a.x; h[1] = (__bf16)a.y; h[2] = (__bf16)a.z; h[3] = (__bf16)a.w;
        h[4] = (__bf16)b.x; h[5] = (__bf16)b.y; h[6] = (__bf16)b.z; h[7] = (__bf16)b.w;
        *reinterpret_cast<bf16x8*>(xc + (size_t)i * 8) = h;
    }
}

// ---------------------------------------------------------------------------
// Pass 1b: W f32 [K][N] -> Wt bf16 [N][K] (transpose via LDS 64x64 tile).
// ---------------------------------------------------------------------------
__global__ __launch_bounds__(256)
void cvt_w(const float* __restrict__ W, __bf16* __restrict__ Wt)
{
    __shared__ __bf16 tile[64][72];   // [k][n], pad 72 -> 144B rows, 16B aligned
    const int t  = threadIdx.x;
    const int n0 = blockIdx.x * 64;
    const int k0 = blockIdx.y * 64;

    #pragma unroll
    for (int i = 0; i < 4; ++i) {
        const int k    = (t >> 4) + i * 16;
        const int col4 = (t & 15) * 4;
        const float4 v = *reinterpret_cast<const float4*>(
            W + (size_t)(k0 + k) * HEADS + n0 + col4);
        bf16x4 h;
        h[0] = (__bf16)v.x; h[1] = (__bf16)v.y; h[2] = (__bf16)v.z; h[3] = (__bf16)v.w;
        *reinterpret_cast<bf16x4*>(&tile[k][col4]) = h;
    }
    __syncthreads();
    #pragma unroll
    for (int i = 0; i < 4; ++i) {
        const int n  = (t >> 4) + i * 16;
        const int k4 = (t & 15) * 4;
        bf16x4 h;
        h[0] = tile[k4 + 0][n]; h[1] = tile[k4 + 1][n];
        h[2] = tile[k4 + 2][n]; h[3] = tile[k4 + 3][n];
        *reinterpret_cast<bf16x4*>(Wt + (size_t)(n0 + n) * HIDDEN + k0 + k4) = h;
    }
}

// ---------------------------------------------------------------------------
// Pass 2: bf16 GEMM, m97 structure: 128x128 tile, BK=64, global_load_lds(16B),
// linear LDS, 4 waves (2x2), sigmoid+bias epilogue.
// ---------------------------------------------------------------------------
__device__ __forceinline__ void gload_lds16(const __bf16* g, __bf16* l)
{
    __builtin_amdgcn_global_load_lds(
        (const __attribute__((address_space(1))) unsigned int*)g,
        (__attribute__((address_space(3))) unsigned int*)l,
        16, 0, 0);
}

#define GBM 128
#define GBN 128
#define GBK 64

__global__ __launch_bounds__(256)
void gemm_bt(const __bf16* __restrict__ A, const __bf16* __restrict__ Bt,
             const float* __restrict__ bias, float* __restrict__ out)
{
    __shared__ __bf16 As[GBM * GBK];   // [row][k] linear, row = 128B
    __shared__ __bf16 Bs[GBN * GBK];   // [col][k] linear

    const int t    = threadIdx.x;
    const int lane = t & 63;
    const int w    = t >> 6;
    const int wr   = w >> 1;
    const int wc   = w & 1;
    const int lhi  = lane >> 4;   // 0..3
    const int llo  = lane & 15;   // 0..15

    const int bm0 = blockIdx.x * GBM;
    const int bn0 = blockIdx.y * GBN;

    // staging coords: per wave-instr seg of 8 rows (1 KB)
    const int srow  = lane >> 3;  // 0..7 within seg
    const int schnk = lane & 7;   // 16B chunk within 128B row

    f32x4 acc[4][4];
    #pragma unroll
    for (int i = 0; i < 4; ++i)
        #pragma unroll
        for (int j = 0; j < 4; ++j)
            acc[i][j] = f32x4{0.f, 0.f, 0.f, 0.f};

    for (int k0 = 0; k0 < HIDDEN; k0 += GBK) {
        #pragma unroll
        for (int i = 0; i < 4; ++i) {
            const int seg = w * 4 + i;            // 0..15
            const int row = seg * 8 + srow;       // 0..127
            gload_lds16(A + (size_t)(bm0 + row) * HIDDEN + k0 + schnk * 8,
                        As + seg * 512 + lane * 8);
            gload_lds16(Bt + (size_t)(bn0 + row) * HIDDEN + k0 + schnk * 8,
                        Bs + seg * 512 + lane * 8);
        }
        __syncthreads();

        #pragma unroll
        for (int ks = 0; ks < 2; ++ks) {
            bf16x8 af[4], bfr[4];
            #pragma unroll
            for (int i = 0; i < 4; ++i)
                af[i] = *reinterpret_cast<const bf16x8*>(
                    &As[(wr * 64 + i * 16 + llo) * GBK + ks * 32 + lhi * 8]);
            #pragma unroll
            for (int j = 0; j < 4; ++j)
                bfr[j] = *reinterpret_cast<const bf16x8*>(
                    &Bs[(wc * 64 + j * 16 + llo) * GBK + ks * 32 + lhi * 8]);
            #pragma unroll
            for (int i = 0; i < 4; ++i)
                #pragma unroll
                for (int j = 0; j < 4; ++j)
                    acc[i][j] = __builtin_amdgcn_mfma_f32_16x16x32_bf16(
                        af[i], bfr[j], acc[i][j], 0, 0, 0);
        }
        __syncthreads();
    }

    // epilogue: bias + sigmoid; C/D: col = lane&15, row = (lane>>4)*4 + reg
    #pragma unroll
    for (int j = 0; j < 4; ++j) {
        const int col    = bn0 + wc * 64 + j * 16 + llo;
        const float bv   = bias[col];
        #pragma unroll
        for (int i = 0; i < 4; ++i) {
            const int row0 = bm0 + wr * 64 + i * 16 + lhi * 4;
            #pragma unroll
            for (int r = 0; r < 4; ++r) {
                const float z = acc[i][j][r] + bv;
                out[(size_t)(row0 + r) * HEADS + col] = 1.0f / (1.0f + __expf(-z));
            }
        }
    }
}

// ---------------------------------------------------------------------------
// Fallback (R1 kernel): fused single-pass, used only if ws too small.
// ---------------------------------------------------------------------------
#define BM 128
#define BN 128
#define BK 32
#define LDK 40

__global__ __launch_bounds__(256)
void lch_gemm(const float* __restrict__ x, const float* __restrict__ W,
              const float* __restrict__ b, float* __restrict__ out)
{
    __shared__ __bf16 As[BM][LDK];
    __shared__ __bf16 Bs[BN][LDK];

    const int t   = threadIdx.x;
    const int bm0 = blockIdx.x * BM;
    const int bn0 = blockIdx.y * BN;
    const int lane = t & 63;
    const int wid  = t >> 6;
    const int wr   = wid >> 1;
    const int wc   = wid & 1;
    const int lhi  = lane >> 4;
    const int llo  = lane & 15;

    f32x4 acc[4][4];
    #pragma unroll
    for (int i = 0; i < 4; ++i)
        #pragma unroll
        for (int j = 0; j < 4; ++j)
            acc[i][j] = f32x4{0.f, 0.f, 0.f, 0.f};

    const int bn_col  = t & 127;
    const int bk_base = (t >> 7) * 16;

    for (int k0 = 0; k0 < HIDDEN; k0 += BK) {
        #pragma unroll
        for (int i = 0; i < 4; ++i) {
            const int f   = t + i * 256;
            const int row = f >> 3;
            const int c4  = (f & 7) * 4;
            const float4 v = *reinterpret_cast<const float4*>(
                x + (size_t)(bm0 + row) * HIDDEN + k0 + c4);
            bf16x4 h;
            h[0] = (__bf16)v.x; h[1] = (__bf16)v.y;
            h[2] = (__bf16)v.z; h[3] = (__bf16)v.w;
            *reinterpret_cast<bf16x4*>(&As[row][c4]) = h;
        }
        {
            const float* wp = W + (size_t)(k0 + bk_base) * HEADS + bn0 + bn_col;
            bf16x8 h0, h1;
            #pragma unroll
            for (int i = 0; i < 8; ++i) h0[i] = (__bf16)wp[(size_t)i * HEADS];
            #pragma unroll
            for (int i = 0; i < 8; ++i) h1[i] = (__bf16)wp[(size_t)(i + 8) * HEADS];
            *reinterpret_cast<bf16x8*>(&Bs[bn_col][bk_base])     = h0;
            *reinterpret_cast<bf16x8*>(&Bs[bn_col][bk_base + 8]) = h1;
        }
        __syncthreads();

        bf16x8 af[4], bfr[4];
        #pragma unroll
        for (int i = 0; i < 4; ++i)
            af[i] = *reinterpret_cast<const bf16x8*>(&As[wr * 64 + i * 16 + llo][lhi * 8]);
        #pragma unroll
        for (int j = 0; j < 4; ++j)
            bfr[j] = *reinterpret_cast<const bf16x8*>(&Bs[wc * 64 + j * 16 + llo][lhi * 8]);
        #pragma unroll
        for (int i = 0; i < 4; ++i)
            #pragma unroll
            for (int j = 0; j < 4; ++j)
                acc[i][j] = __builtin_amdgcn_mfma_f32_16x16x32_bf16(
                    af[i], bfr[j], acc[i][j], 0, 0, 0);
        __syncthreads();
    }

    #pragma unroll
    for (int j = 0; j < 4; ++j) {
        const int col  = bn0 + wc * 64 + j * 16 + llo;
        const float bv = b[col];
        #pragma unroll
        for (int i = 0; i < 4; ++i) {
            const int row0 = bm0 + wr * 64 + i * 16 + lhi * 4;
            #pragma unroll
            for (int r = 0; r < 4; ++r) {
                const float z = acc[i][j][r] + bv;
                out[(size_t)(row0 + r) * HEADS + col] = 1.0f / (1.0f + __expf(-z));
            }
        }
    }
}

extern "C" void kernel_launch(void* const* d_in, const int* in_sizes, int n_in,
                              void* d_out, int out_size, void* d_ws, size_t ws_size,
                              hipStream_t stream) {
    const float* x = (const float*)d_in[0];
    const float* W = (const float*)d_in[1];
    const float* b = (const float*)d_in[2];
    float* out     = (float*)d_out;

    const int M = in_sizes[0] / HIDDEN;   // 8192

    const size_t xc_bytes = (size_t)M * HIDDEN * sizeof(__bf16);
    const size_t wt_bytes = (size_t)HEADS * HIDDEN * sizeof(__bf16);

    if (ws_size >= xc_bytes + wt_bytes) {
        __bf16* xc = (__bf16*)d_ws;
        __bf16* Wt = (__bf16*)((char*)d_ws + xc_bytes);

        const int n8 = M * HIDDEN / 8;
        cvt_x<<<2048, 256, 0, stream>>>(x, xc, n8);
        cvt_w<<<dim3(HEADS / 64, HIDDEN / 64), 256, 0, stream>>>(W, Wt);

        dim3 grid(M / GBM, HEADS / GBN);  // (64, 20)
        gemm_bt<<<grid, dim3(256), 0, stream>>>(xc, Wt, b, out);
    } else {
        dim3 grid(M / BM, HEADS / BN);
        lch_gemm<<<grid, dim3(256), 0, stream>>>(x, W, b, out);
    }
}

// Round 3
// 95.057 us; speedup vs baseline: 1.0253x; 1.0199x over previous
//
#include <hip/hip_runtime.h>
#include <hip/hip_bf16.h>

#define HIDDEN 1024
#define HEADS  2560

// GEMM tile geometry
#define BM 256
#define BN 128
#define BK 64
#define NT (HIDDEN / BK)          // 16 K-tiles
#define ABYTES (BM * BK * 2)      // 32768
#define BBYTES (BN * BK * 2)      // 16384
#define BUFSZ  (ABYTES + BBYTES)  // 49152
#define NBUF 3                    // 144 KB LDS ring

typedef float  f32x4  __attribute__((ext_vector_type(4)));
typedef __bf16 bf16x8 __attribute__((ext_vector_type(8)));
typedef __bf16 bf16x4 __attribute__((ext_vector_type(4)));

__device__ __forceinline__ void gload_lds16(const void* g, void* l) {
    __builtin_amdgcn_global_load_lds(
        (const __attribute__((address_space(1))) unsigned int*)g,
        (__attribute__((address_space(3))) unsigned int*)l, 16, 0, 0);
}
// st_16x32 swizzle: XOR byte-bit-5 with bit-9 (involution within 1024B subtile)
__device__ __forceinline__ unsigned swz(unsigned b) {
    return b ^ (((b >> 9) & 1u) << 5);
}

// ---------------------------------------------------------------------------
// Pass 1a: x f32 -> bf16
// ---------------------------------------------------------------------------
__global__ __launch_bounds__(256)
void cvt_x(const float* __restrict__ x, __bf16* __restrict__ xc, int n8)
{
    int idx = blockIdx.x * blockDim.x + threadIdx.x;
    int stride = gridDim.x * blockDim.x;
    for (int i = idx; i < n8; i += stride) {
        const float4 a = *reinterpret_cast<const float4*>(x + (size_t)i * 8);
        const float4 b = *reinterpret_cast<const float4*>(x + (size_t)i * 8 + 4);
        bf16x8 h;
        h[0] = (__bf16)a.x; h[1] = (__bf16)a.y; h[2] = (__bf16)a.z; h[3] = (__bf16)a.w;
        h[4] = (__bf16)b.x; h[5] = (__bf16)b.y; h[6] = (__bf16)b.z; h[7] = (__bf16)b.w;
        *reinterpret_cast<bf16x8*>(xc + (size_t)i * 8) = h;
    }
}

// ---------------------------------------------------------------------------
// Pass 1b: W f32 [K][N] -> Wt bf16 [N][K]
// ---------------------------------------------------------------------------
__global__ __launch_bounds__(256)
void cvt_w(const float* __restrict__ W, __bf16* __restrict__ Wt)
{
    __shared__ __bf16 tile[64][72];
    const int t  = threadIdx.x;
    const int n0 = blockIdx.x * 64;
    const int k0 = blockIdx.y * 64;

    #pragma unroll
    for (int i = 0; i < 4; ++i) {
        const int k    = (t >> 4) + i * 16;
        const int col4 = (t & 15) * 4;
        const float4 v = *reinterpret_cast<const float4*>(
            W + (size_t)(k0 + k) * HEADS + n0 + col4);
        bf16x4 h;
        h[0] = (__bf16)v.x; h[1] = (__bf16)v.y; h[2] = (__bf16)v.z; h[3] = (__bf16)v.w;
        *reinterpret_cast<bf16x4*>(&tile[k][col4]) = h;
    }
    __syncthreads();
    #pragma unroll
    for (int i = 0; i < 4; ++i) {
        const int n  = (t >> 4) + i * 16;
        const int k4 = (t & 15) * 4;
        bf16x4 h;
        h[0] = tile[k4 + 0][n]; h[1] = tile[k4 + 1][n];
        h[2] = tile[k4 + 2][n]; h[3] = tile[k4 + 3][n];
        *reinterpret_cast<bf16x4*>(Wt + (size_t)(n0 + n) * HIDDEN + k0 + k4) = h;
    }
}

// ---------------------------------------------------------------------------
// Pass 2: phase-split pipelined bf16 GEMM (T2+T3+T4+T5), 3-buffer LDS ring.
//   256x128 tile, BK=64, 8 waves (4M x 2N), per-wave 64x64 = acc[4][4].
//   Per K-tile: 2 phases (ks=0,1), each {8 ds_read | 3 gload_lds | barrier |
//   lgkmcnt(0) | setprio(1) 16 MFMA setprio(0) | barrier}; vmcnt(6) once per
//   K-tile (counted, never 0 in steady state). Raw s_barrier throughout --
//   __syncthreads would emit the vmcnt(0) drain this schedule exists to avoid.
// Race-freedom: iter k reads buf k%3 (completed: prev iter vmcnt(6)+barrier);
//   stages T(k+2) into buf (k+2)%3, whose last reader was iter k-1 (reads
//   complete before iter k-1's final barrier -> before these writes issue).
// ---------------------------------------------------------------------------
__global__ __launch_bounds__(512)
void gemm8p(const __bf16* __restrict__ A, const __bf16* __restrict__ Bt,
            const float* __restrict__ bias, float* __restrict__ out)
{
    __shared__ char lds[NBUF * BUFSZ];   // 144 KB

    const int t    = threadIdx.x;
    const int lane = t & 63;
    const int w    = t >> 6;       // 0..7
    const int wr   = w >> 1;       // 0..3 : 64-row slab
    const int wc   = w & 1;        // 0..1 : 64-col slab
    const int lhi  = lane >> 4;
    const int llo  = lane & 15;

    // XCD-aware bijective swizzle (nwg=640, 640%8==0)
    const int cpx = gridDim.x >> 3;
    int bid = (blockIdx.x & 7) * cpx + (blockIdx.x >> 3);
    const int bx  = bid & 31;      // M-block (fastest -> same XCD shares W panel)
    const int by  = bid >> 5;      // N-block
    const int bm0 = bx * BM;
    const int bn0 = by * BN;

    // ---- staging descriptors: linear LDS dest b, inverse-swizzled global src
    const char* a_src[4]; unsigned a_dst[4];
    const char* b_src[2]; unsigned b_dst[2];
    #pragma unroll
    for (int l = 0; l < 4; ++l) {
        unsigned b = (unsigned)(t * 16 + l * 8192);
        unsigned p = swz(b);
        a_src[l] = (const char*)(A + (size_t)(bm0 + (p >> 7)) * HIDDEN) + (p & 127);
        a_dst[l] = b;
    }
    #pragma unroll
    for (int l = 0; l < 2; ++l) {
        unsigned b = (unsigned)(t * 16 + l * 8192);
        unsigned p = swz(b);
        b_src[l] = (const char*)(Bt + (size_t)(bn0 + (p >> 7)) * HIDDEN) + (p & 127);
        b_dst[l] = (unsigned)ABYTES + b;
    }

    // ---- fragment read offsets (swizzled), loop-invariant
    const unsigned xa = ((llo >> 2) & 1u) << 5;
    unsigned offA[4], offB[4];
    #pragma unroll
    for (int m = 0; m < 4; ++m)
        offA[m] = (unsigned)((wr * 64 + m * 16 + llo) * 128 + lhi * 16) ^ xa;
    #pragma unroll
    for (int n = 0; n < 4; ++n)
        offB[n] = ((unsigned)ABYTES + (unsigned)((wc * 64 + n * 16 + llo) * 128 + lhi * 16)) ^ xa;

    f32x4 acc[4][4];
    #pragma unroll
    for (int m = 0; m < 4; ++m)
        #pragma unroll
        for (int n = 0; n < 4; ++n)
            acc[m][n] = f32x4{0.f, 0.f, 0.f, 0.f};

    // ---- prologue: stage T0 -> buf0, T1 -> buf1 (12 loads), wait T0, barrier
    #pragma unroll
    for (int l = 0; l < 4; ++l) gload_lds16(a_src[l],       lds + a_dst[l]);
    #pragma unroll
    for (int l = 0; l < 2; ++l) gload_lds16(b_src[l],       lds + b_dst[l]);
    #pragma unroll
    for (int l = 0; l < 4; ++l) gload_lds16(a_src[l] + 128, lds + BUFSZ + a_dst[l]);
    #pragma unroll
    for (int l = 0; l < 2; ++l) gload_lds16(b_src[l] + 128, lds + BUFSZ + b_dst[l]);
    asm volatile("s_waitcnt vmcnt(6)" ::: "memory");
    __builtin_amdgcn_s_barrier();

    // ---- main loop
    for (int k = 0; k < NT; ++k) {
        const int  bi  = k % 3;
        const int  bnx = (k + 2) % 3;
        const char* buf = lds + bi * BUFSZ;
        char*       nbf = lds + bnx * BUFSZ;
        const bool st  = (k + 2 < NT);
        const int  koff = (k + 2) * 128;   // byte advance for staged K-tile

        bf16x8 af[4], bf[4];

        // ======== phase 0 (ks = 0) ========
        #pragma unroll
        for (int m = 0; m < 4; ++m) af[m] = *(const bf16x8*)(buf + offA[m]);
        #pragma unroll
        for (int n = 0; n < 4; ++n) bf[n] = *(const bf16x8*)(buf + offB[n]);
        if (st) {
            gload_lds16(a_src[0] + koff, nbf + a_dst[0]);
            gload_lds16(a_src[1] + koff, nbf + a_dst[1]);
            gload_lds16(a_src[2] + koff, nbf + a_dst[2]);
        }
        __builtin_amdgcn_s_barrier();
        asm volatile("s_waitcnt lgkmcnt(0)" ::: "memory");
        __builtin_amdgcn_sched_barrier(0);
        __builtin_amdgcn_s_setprio(1);
        #pragma unroll
        for (int m = 0; m < 4; ++m)
            #pragma unroll
            for (int n = 0; n < 4; ++n)
                acc[m][n] = __builtin_amdgcn_mfma_f32_16x16x32_bf16(
                    af[m], bf[n], acc[m][n], 0, 0, 0);
        __builtin_amdgcn_s_setprio(0);
        __builtin_amdgcn_s_barrier();

        // ======== phase 1 (ks = 1) ========
        #pragma unroll
        for (int m = 0; m < 4; ++m) af[m] = *(const bf16x8*)(buf + offA[m] + 64);
        #pragma unroll
        for (int n = 0; n < 4; ++n) bf[n] = *(const bf16x8*)(buf + offB[n] + 64);
        if (st) {
            gload_lds16(a_src[3] + koff, nbf + a_dst[3]);
            gload_lds16(b_src[0] + koff, nbf + b_dst[0]);
            gload_lds16(b_src[1] + koff, nbf + b_dst[1]);
        }
        if (k < NT - 2)       asm volatile("s_waitcnt vmcnt(6)" ::: "memory");
        else if (k == NT - 2) asm volatile("s_waitcnt vmcnt(0)" ::: "memory");
        __builtin_amdgcn_s_barrier();
        asm volatile("s_waitcnt lgkmcnt(0)" ::: "memory");
        __builtin_amdgcn_sched_barrier(0);
        __builtin_amdgcn_s_setprio(1);
        #pragma unroll
        for (int m = 0; m < 4; ++m)
            #pragma unroll
            for (int n = 0; n < 4; ++n)
                acc[m][n] = __builtin_amdgcn_mfma_f32_16x16x32_bf16(
                    af[m], bf[n], acc[m][n], 0, 0, 0);
        __builtin_amdgcn_s_setprio(0);
        __builtin_amdgcn_s_barrier();
    }

    // ---- epilogue: bias + sigmoid; C/D: col = lane&15, row = (lane>>4)*4+reg
    #pragma unroll
    for (int n = 0; n < 4; ++n) {
        const int col  = bn0 + wc * 64 + n * 16 + llo;
        const float bv = bias[col];
        #pragma unroll
        for (int m = 0; m < 4; ++m) {
            const int row0 = bm0 + wr * 64 + m * 16 + lhi * 4;
            #pragma unroll
            for (int r = 0; r < 4; ++r) {
                const float z = acc[m][n][r] + bv;
                out[(size_t)(row0 + r) * HEADS + col] = 1.0f / (1.0f + __expf(-z));
            }
        }
    }
}

// ---------------------------------------------------------------------------
// Fallback (R1 fused kernel) if workspace is too small.
// ---------------------------------------------------------------------------
#define FBM 128
#define FBN 128
#define FBK 32
#define FLDK 40

__global__ __launch_bounds__(256)
void lch_gemm(const float* __restrict__ x, const float* __restrict__ W,
              const float* __restrict__ b, float* __restrict__ out)
{
    __shared__ __bf16 As[FBM][FLDK];
    __shared__ __bf16 Bs[FBN][FLDK];

    const int t   = threadIdx.x;
    const int bm0 = blockIdx.x * FBM;
    const int bn0 = blockIdx.y * FBN;
    const int lane = t & 63;
    const int wid  = t >> 6;
    const int wr   = wid >> 1;
    const int wc   = wid & 1;
    const int lhi  = lane >> 4;
    const int llo  = lane & 15;

    f32x4 acc[4][4];
    #pragma unroll
    for (int i = 0; i < 4; ++i)
        #pragma unroll
        for (int j = 0; j < 4; ++j)
            acc[i][j] = f32x4{0.f, 0.f, 0.f, 0.f};

    const int bn_col  = t & 127;
    const int bk_base = (t >> 7) * 16;

    for (int k0 = 0; k0 < HIDDEN; k0 += FBK) {
        #pragma unroll
        for (int i = 0; i < 4; ++i) {
            const int f   = t + i * 256;
            const int row = f >> 3;
            const int c4  = (f & 7) * 4;
            const float4 v = *reinterpret_cast<const float4*>(
                x + (size_t)(bm0 + row) * HIDDEN + k0 + c4);
            bf16x4 h;
            h[0] = (__bf16)v.x; h[1] = (__bf16)v.y;
            h[2] = (__bf16)v.z; h[3] = (__bf16)v.w;
            *reinterpret_cast<bf16x4*>(&As[row][c4]) = h;
        }
        {
            const float* wp = W + (size_t)(k0 + bk_base) * HEADS + bn0 + bn_col;
            bf16x8 h0, h1;
            #pragma unroll
            for (int i = 0; i < 8; ++i) h0[i] = (__bf16)wp[(size_t)i * HEADS];
            #pragma unroll
            for (int i = 0; i < 8; ++i) h1[i] = (__bf16)wp[(size_t)(i + 8) * HEADS];
            *reinterpret_cast<bf16x8*>(&Bs[bn_col][bk_base])     = h0;
            *reinterpret_cast<bf16x8*>(&Bs[bn_col][bk_base + 8]) = h1;
        }
        __syncthreads();

        bf16x8 af[4], bfr[4];
        #pragma unroll
        for (int i = 0; i < 4; ++i)
            af[i] = *reinterpret_cast<const bf16x8*>(&As[wr * 64 + i * 16 + llo][lhi * 8]);
        #pragma unroll
        for (int j = 0; j < 4; ++j)
            bfr[j] = *reinterpret_cast<const bf16x8*>(&Bs[wc * 64 + j * 16 + llo][lhi * 8]);
        #pragma unroll
        for (int i = 0; i < 4; ++i)
            #pragma unroll
            for (int j = 0; j < 4; ++j)
                acc[i][j] = __builtin_amdgcn_mfma_f32_16x16x32_bf16(
                    af[i], bfr[j], acc[i][j], 0, 0, 0);
        __syncthreads();
    }

    #pragma unroll
    for (int j = 0; j < 4; ++j) {
        const int col  = bn0 + wc * 64 + j * 16 + llo;
        const float bv = b[col];
        #pragma unroll
        for (int i = 0; i < 4; ++i) {
            const int row0 = bm0 + wr * 64 + i * 16 + lhi * 4;
            #pragma unroll
            for (int r = 0; r < 4; ++r) {
                const float z = acc[i][j][r] + bv;
                out[(size_t)(row0 + r) * HEADS + col] = 1.0f / (1.0f + __expf(-z));
            }
        }
    }
}

extern "C" void kernel_launch(void* const* d_in, const int* in_sizes, int n_in,
                              void* d_out, int out_size, void* d_ws, size_t ws_size,
                              hipStream_t stream) {
    const float* x = (const float*)d_in[0];
    const float* W = (const float*)d_in[1];
    const float* b = (const float*)d_in[2];
    float* out     = (float*)d_out;

    const int M = in_sizes[0] / HIDDEN;   // 8192

    const size_t xc_bytes = (size_t)M * HIDDEN * sizeof(__bf16);
    const size_t wt_bytes = (size_t)HEADS * HIDDEN * sizeof(__bf16);

    if (ws_size >= xc_bytes + wt_bytes) {
        __bf16* xc = (__bf16*)d_ws;
        __bf16* Wt = (__bf16*)((char*)d_ws + xc_bytes);

        cvt_x<<<2048, 256, 0, stream>>>(x, xc, M * HIDDEN / 8);
        cvt_w<<<dim3(HEADS / 64, HIDDEN / 64), 256, 0, stream>>>(W, Wt);

        const int nwg = (M / BM) * (HEADS / BN);   // 32 * 20 = 640
        gemm8p<<<nwg, 512, 0, stream>>>(xc, Wt, b, out);
    } else {
        dim3 grid(M / FBM, HEADS / FBN);
        lch_gemm<<<grid, dim3(256), 0, stream>>>(x, W, b, out);
    }
}

// Round 4
// 68.976 us; speedup vs baseline: 1.4130x; 1.3781x over previous
//
#include <hip/hip_runtime.h>
#include <hip/hip_bf16.h>

#define HIDDEN 1024
#define HEADS  2560

// GEMM geometry: 256x320 tile, BK=64, grid = (M/256)*(2560/320) = 32*8 = 256 = 1 block/CU
#define BM 256
#define BN 320
#define BK 64
#define NT (HIDDEN / BK)         // 16 K-tiles
#define AREG 0
#define ABYTES (BM * BK * 2)     // 32768
#define BBYTES (BN * BK * 2)     // 40960
#define BUFSZ  (ABYTES + BBYTES) // 73728
// LDS = 2 * 73728 = 147456 (1 block/CU)

typedef float  f32x4  __attribute__((ext_vector_type(4)));
typedef __bf16 bf16x8 __attribute__((ext_vector_type(8)));
typedef __bf16 bf16x4 __attribute__((ext_vector_type(4)));

__device__ __forceinline__ void gload_lds16(const void* g, void* l) {
    __builtin_amdgcn_global_load_lds(
        (const __attribute__((address_space(1))) unsigned int*)g,
        (__attribute__((address_space(3))) unsigned int*)l, 16, 0, 0);
}
// Read swizzle: logical byte x (row = x>>7, 128B rows) lives at x ^ ((row&7)<<4).
// Involution (bits 7..9 untouched). Spreads a 16-lane column read over all 8
// 16B chunks of the row -> 2-way residual bank aliasing (free, m136).
__device__ __forceinline__ unsigned swz(unsigned x) {
    return x ^ (((x >> 7) & 7u) << 4);
}

// ---------------------------------------------------------------------------
// Pass 1a: x f32 -> bf16
// ---------------------------------------------------------------------------
__global__ __launch_bounds__(256)
void cvt_x(const float* __restrict__ x, __bf16* __restrict__ xc, int n8)
{
    int idx = blockIdx.x * blockDim.x + threadIdx.x;
    int stride = gridDim.x * blockDim.x;
    for (int i = idx; i < n8; i += stride) {
        const float4 a = *reinterpret_cast<const float4*>(x + (size_t)i * 8);
        const float4 b = *reinterpret_cast<const float4*>(x + (size_t)i * 8 + 4);
        bf16x8 h;
        h[0] = (__bf16)a.x; h[1] = (__bf16)a.y; h[2] = (__bf16)a.z; h[3] = (__bf16)a.w;
        h[4] = (__bf16)b.x; h[5] = (__bf16)b.y; h[6] = (__bf16)b.z; h[7] = (__bf16)b.w;
        *reinterpret_cast<bf16x8*>(xc + (size_t)i * 8) = h;
    }
}

// ---------------------------------------------------------------------------
// Pass 1b: W f32 [K][N] -> Wt bf16 [N][K]
// ---------------------------------------------------------------------------
__global__ __launch_bounds__(256)
void cvt_w(const float* __restrict__ W, __bf16* __restrict__ Wt)
{
    __shared__ __bf16 tile[64][72];
    const int t  = threadIdx.x;
    const int n0 = blockIdx.x * 64;
    const int k0 = blockIdx.y * 64;

    #pragma unroll
    for (int i = 0; i < 4; ++i) {
        const int k    = (t >> 4) + i * 16;
        const int col4 = (t & 15) * 4;
        const float4 v = *reinterpret_cast<const float4*>(
            W + (size_t)(k0 + k) * HEADS + n0 + col4);
        bf16x4 h;
        h[0] = (__bf16)v.x; h[1] = (__bf16)v.y; h[2] = (__bf16)v.z; h[3] = (__bf16)v.w;
        *reinterpret_cast<bf16x4*>(&tile[k][col4]) = h;
    }
    __syncthreads();
    #pragma unroll
    for (int i = 0; i < 4; ++i) {
        const int n  = (t >> 4) + i * 16;
        const int k4 = (t & 15) * 4;
        bf16x4 h;
        h[0] = tile[k4 + 0][n]; h[1] = tile[k4 + 1][n];
        h[2] = tile[k4 + 2][n]; h[3] = tile[k4 + 3][n];
        *reinterpret_cast<bf16x4*>(Wt + (size_t)(n0 + n) * HIDDEN + k0 + k4) = h;
    }
}

// ---------------------------------------------------------------------------
// Pass 2: 256x320 tile, 8 waves (2M x 4N), per-wave 128x80, acc[8][5].
// 4 phases per K-tile (kk x m-half), 20 MFMA each; stages post-MFMA; one
// vmcnt(0) per K-tile (issued >=1 phase after last stage); XOR-swizzled LDS.
// ---------------------------------------------------------------------------
__global__ __launch_bounds__(512, 2)
void gemm_p4(const __bf16* __restrict__ A, const __bf16* __restrict__ Bt,
             const float* __restrict__ bias, float* __restrict__ out)
{
    __shared__ char lds[2 * BUFSZ];

    const int t    = threadIdx.x;
    const int lane = t & 63;
    const int w    = t >> 6;      // 0..7
    const int wr   = w >> 2;      // 0..1 : 128-row slab
    const int wc   = w & 3;       // 0..3 : 80-col slab
    const int lhi  = lane >> 4;   // 0..3
    const int llo  = lane & 15;   // 0..15

    // by = bid&7 -> each XCD's 32 concurrent blocks share one B-panel (640KB, L2-resident)
    const int by  = blockIdx.x & 7;
    const int bx  = blockIdx.x >> 3;
    const int bm0 = bx * BM;
    const int bn0 = by * BN;

    // ---- stage descriptors: linear LDS dest d, source pre-swizzled (rule 21)
    const char* asrc[4]; unsigned adst[4];
    #pragma unroll
    for (int li = 0; li < 4; ++li) {
        unsigned d = (unsigned)(li * 8192 + t * 16);
        unsigned L = swz(d);
        asrc[li] = (const char*)A + (size_t)(bm0 + (L >> 7)) * (HIDDEN * 2) + (L & 127);
        adst[li] = d;
    }
    const char* bsrc[5]; unsigned bdst[5];
    #pragma unroll
    for (int li = 0; li < 5; ++li) {
        unsigned d = (unsigned)(li * 8192 + t * 16);
        unsigned L = swz(d);
        bsrc[li] = (const char*)Bt + (size_t)(bn0 + (L >> 7)) * (HIDDEN * 2) + (L & 127);
        bdst[li] = (unsigned)ABYTES + d;
    }

    // ---- fragment read offsets
    const unsigned xa   = (unsigned)((llo & 7) << 4);
    const unsigned klo0 = ((unsigned)(lhi * 16)) ^ xa;        // kk = 0
    const unsigned klo1 = ((unsigned)(64 + lhi * 16)) ^ xa;   // kk = 1
    unsigned offA[8], offB[5];
    #pragma unroll
    for (int m = 0; m < 8; ++m)
        offA[m] = (unsigned)((wr * 128 + m * 16 + llo) * 128);
    #pragma unroll
    for (int n = 0; n < 5; ++n)
        offB[n] = (unsigned)ABYTES + (unsigned)((wc * 80 + n * 16 + llo) * 128);

    f32x4 acc[8][5];
    #pragma unroll
    for (int m = 0; m < 8; ++m)
        #pragma unroll
        for (int n = 0; n < 5; ++n)
            acc[m][n] = f32x4{0.f, 0.f, 0.f, 0.f};

    // ---- prologue: stage T0 -> buf0
    #pragma unroll
    for (int li = 0; li < 4; ++li) gload_lds16(asrc[li], lds + adst[li]);
    #pragma unroll
    for (int li = 0; li < 5; ++li) gload_lds16(bsrc[li], lds + bdst[li]);
    asm volatile("s_waitcnt vmcnt(0)" ::: "memory");
    __builtin_amdgcn_s_barrier();

    for (int k = 0; k < NT; ++k) {
        const char* buf = lds + (k & 1) * BUFSZ;
        char*       nbf = lds + ((k + 1) & 1) * BUFSZ;
        const bool  st  = (k + 1 < NT);
        const int   koff = (k + 1) * 128;

        bf16x8 af[4], bfr[5];

        // ======== P0: kk0, m0-3 (9 ds_read) ========
        #pragma unroll
        for (int m = 0; m < 4; ++m) af[m]  = *(const bf16x8*)(buf + (offA[m] + klo0));
        #pragma unroll
        for (int n = 0; n < 5; ++n) bfr[n] = *(const bf16x8*)(buf + (offB[n] + klo0));
        __builtin_amdgcn_s_barrier();
        asm volatile("s_waitcnt lgkmcnt(0)" ::: "memory");
        __builtin_amdgcn_sched_barrier(0);
        __builtin_amdgcn_s_setprio(1);
        #pragma unroll
        for (int m = 0; m < 4; ++m)
            #pragma unroll
            for (int n = 0; n < 5; ++n)
                acc[m][n] = __builtin_amdgcn_mfma_f32_16x16x32_bf16(
                    af[m], bfr[n], acc[m][n], 0, 0, 0);
        __builtin_amdgcn_s_setprio(0);
        if (st) {
            gload_lds16(asrc[0] + koff, nbf + adst[0]);
            gload_lds16(asrc[1] + koff, nbf + adst[1]);
            gload_lds16(asrc[2] + koff, nbf + adst[2]);
        }
        __builtin_amdgcn_s_barrier();

        // ======== P1: kk0, m4-7 (4 ds_read, reuse bfr) ========
        #pragma unroll
        for (int m = 0; m < 4; ++m) af[m] = *(const bf16x8*)(buf + (offA[m + 4] + klo0));
        __builtin_amdgcn_s_barrier();
        asm volatile("s_waitcnt lgkmcnt(0)" ::: "memory");
        __builtin_amdgcn_sched_barrier(0);
        __builtin_amdgcn_s_setprio(1);
        #pragma unroll
        for (int m = 0; m < 4; ++m)
            #pragma unroll
            for (int n = 0; n < 5; ++n)
                acc[m + 4][n] = __builtin_amdgcn_mfma_f32_16x16x32_bf16(
                    af[m], bfr[n], acc[m + 4][n], 0, 0, 0);
        __builtin_amdgcn_s_setprio(0);
        if (st) {
            gload_lds16(asrc[3] + koff, nbf + adst[3]);
            gload_lds16(bsrc[0] + koff, nbf + bdst[0]);
            gload_lds16(bsrc[1] + koff, nbf + bdst[1]);
        }
        __builtin_amdgcn_s_barrier();

        // ======== P2: kk1, m0-3 (9 ds_read) ========
        #pragma unroll
        for (int m = 0; m < 4; ++m) af[m]  = *(const bf16x8*)(buf + (offA[m] + klo1));
        #pragma unroll
        for (int n = 0; n < 5; ++n) bfr[n] = *(const bf16x8*)(buf + (offB[n] + klo1));
        __builtin_amdgcn_s_barrier();
        asm volatile("s_waitcnt lgkmcnt(0)" ::: "memory");
        __builtin_amdgcn_sched_barrier(0);
        __builtin_amdgcn_s_setprio(1);
        #pragma unroll
        for (int m = 0; m < 4; ++m)
            #pragma unroll
            for (int n = 0; n < 5; ++n)
                acc[m][n] = __builtin_amdgcn_mfma_f32_16x16x32_bf16(
                    af[m], bfr[n], acc[m][n], 0, 0, 0);
        __builtin_amdgcn_s_setprio(0);
        if (st) {
            gload_lds16(bsrc[2] + koff, nbf + bdst[2]);
            gload_lds16(bsrc[3] + koff, nbf + bdst[3]);
            gload_lds16(bsrc[4] + koff, nbf + bdst[4]);
        }
        __builtin_amdgcn_s_barrier();

        // ======== P3: kk1, m4-7 (4 ds_read) ========
        #pragma unroll
        for (int m = 0; m < 4; ++m) af[m] = *(const bf16x8*)(buf + (offA[m + 4] + klo1));
        __builtin_amdgcn_s_barrier();
        asm volatile("s_waitcnt lgkmcnt(0)" ::: "memory");
        __builtin_amdgcn_sched_barrier(0);
        __builtin_amdgcn_s_setprio(1);
        #pragma unroll
        for (int m = 0; m < 4; ++m)
            #pragma unroll
            for (int n = 0; n < 5; ++n)
                acc[m + 4][n] = __builtin_amdgcn_mfma_f32_16x16x32_bf16(
                    af[m], bfr[n], acc[m + 4][n], 0, 0, 0);
        __builtin_amdgcn_s_setprio(0);
        asm volatile("s_waitcnt vmcnt(0)" ::: "memory");
        __builtin_amdgcn_s_barrier();
    }

    // ---- epilogue: bias + sigmoid; C/D: col = lane&15, row = (lane>>4)*4+reg
    #pragma unroll
    for (int n = 0; n < 5; ++n) {
        const int col  = bn0 + wc * 80 + n * 16 + llo;
        const float bv = bias[col];
        #pragma unroll
        for (int m = 0; m < 8; ++m) {
            const int row0 = bm0 + wr * 128 + m * 16 + lhi * 4;
            #pragma unroll
            for (int r = 0; r < 4; ++r) {
                const float z = acc[m][n][r] + bv;
                out[(size_t)(row0 + r) * HEADS + col] = __fdividef(1.0f, 1.0f + __expf(-z));
            }
        }
    }
}

// ---------------------------------------------------------------------------
// Fallback (R1 fused kernel) if workspace is too small.
// ---------------------------------------------------------------------------
#define FBM 128
#define FBN 128
#define FBK 32
#define FLDK 40

__global__ __launch_bounds__(256)
void lch_gemm(const float* __restrict__ x, const float* __restrict__ W,
              const float* __restrict__ b, float* __restrict__ out)
{
    __shared__ __bf16 As[FBM][FLDK];
    __shared__ __bf16 Bs[FBN][FLDK];

    const int t   = threadIdx.x;
    const int bm0 = blockIdx.x * FBM;
    const int bn0 = blockIdx.y * FBN;
    const int lane = t & 63;
    const int wid  = t >> 6;
    const int wr   = wid >> 1;
    const int wc   = wid & 1;
    const int lhi  = lane >> 4;
    const int llo  = lane & 15;

    f32x4 acc[4][4];
    #pragma unroll
    for (int i = 0; i < 4; ++i)
        #pragma unroll
        for (int j = 0; j < 4; ++j)
            acc[i][j] = f32x4{0.f, 0.f, 0.f, 0.f};

    const int bn_col  = t & 127;
    const int bk_base = (t >> 7) * 16;

    for (int k0 = 0; k0 < HIDDEN; k0 += FBK) {
        #pragma unroll
        for (int i = 0; i < 4; ++i) {
            const int f   = t + i * 256;
            const int row = f >> 3;
            const int c4  = (f & 7) * 4;
            const float4 v = *reinterpret_cast<const float4*>(
                x + (size_t)(bm0 + row) * HIDDEN + k0 + c4);
            bf16x4 h;
            h[0] = (__bf16)v.x; h[1] = (__bf16)v.y;
            h[2] = (__bf16)v.z; h[3] = (__bf16)v.w;
            *reinterpret_cast<bf16x4*>(&As[row][c4]) = h;
        }
        {
            const float* wp = W + (size_t)(k0 + bk_base) * HEADS + bn0 + bn_col;
            bf16x8 h0, h1;
            #pragma unroll
            for (int i = 0; i < 8; ++i) h0[i] = (__bf16)wp[(size_t)i * HEADS];
            #pragma unroll
            for (int i = 0; i < 8; ++i) h1[i] = (__bf16)wp[(size_t)(i + 8) * HEADS];
            *reinterpret_cast<bf16x8*>(&Bs[bn_col][bk_base])     = h0;
            *reinterpret_cast<bf16x8*>(&Bs[bn_col][bk_base + 8]) = h1;
        }
        __syncthreads();

        bf16x8 af[4], bfr[4];
        #pragma unroll
        for (int i = 0; i < 4; ++i)
            af[i] = *reinterpret_cast<const bf16x8*>(&As[wr * 64 + i * 16 + llo][lhi * 8]);
        #pragma unroll
        for (int j = 0; j < 4; ++j)
            bfr[j] = *reinterpret_cast<const bf16x8*>(&Bs[wc * 64 + j * 16 + llo][lhi * 8]);
        #pragma unroll
        for (int i = 0; i < 4; ++i)
            #pragma unroll
            for (int j = 0; j < 4; ++j)
                acc[i][j] = __builtin_amdgcn_mfma_f32_16x16x32_bf16(
                    af[i], bfr[j], acc[i][j], 0, 0, 0);
        __syncthreads();
    }

    #pragma unroll
    for (int j = 0; j < 4; ++j) {
        const int col  = bn0 + wc * 64 + j * 16 + llo;
        const float bv = b[col];
        #pragma unroll
        for (int i = 0; i < 4; ++i) {
            const int row0 = bm0 + wr * 64 + i * 16 + lhi * 4;
            #pragma unroll
            for (int r = 0; r < 4; ++r) {
                const float z = acc[i][j][r] + bv;
                out[(size_t)(row0 + r) * HEADS + col] = 1.0f / (1.0f + __expf(-z));
            }
        }
    }
}

extern "C" void kernel_launch(void* const* d_in, const int* in_sizes, int n_in,
                              void* d_out, int out_size, void* d_ws, size_t ws_size,
                              hipStream_t stream) {
    const float* x = (const float*)d_in[0];
    const float* W = (const float*)d_in[1];
    const float* b = (const float*)d_in[2];
    float* out     = (float*)d_out;

    const int M = in_sizes[0] / HIDDEN;   // 8192

    const size_t xc_bytes = (size_t)M * HIDDEN * sizeof(__bf16);
    const size_t wt_bytes = (size_t)HEADS * HIDDEN * sizeof(__bf16);

    if (ws_size >= xc_bytes + wt_bytes && (M % BM) == 0) {
        __bf16* xc = (__bf16*)d_ws;
        __bf16* Wt = (__bf16*)((char*)d_ws + xc_bytes);

        cvt_x<<<2048, 256, 0, stream>>>(x, xc, M * HIDDEN / 8);
        cvt_w<<<dim3(HEADS / 64, HIDDEN / 64), 256, 0, stream>>>(W, Wt);

        const int nwg = (M / BM) * (HEADS / BN);   // 32 * 8 = 256
        gemm_p4<<<nwg, 512, 0, stream>>>(xc, Wt, b, out);
    } else {
        dim3 grid(M / FBM, HEADS / FBN);
        lch_gemm<<<grid, dim3(256), 0, stream>>>(x, W, b, out);
    }
}

// Round 5
// 67.012 us; speedup vs baseline: 1.4544x; 1.0293x over previous
//
#include <hip/hip_runtime.h>
#include <hip/hip_bf16.h>

#define HIDDEN 1024
#define HEADS  2560

// GEMM geometry: 256x320 tile, BK=64, grid = (8192/256)*(2560/320) = 256 = 1 block/CU
#define BM 256
#define BN 320
#define BK 64
#define NT (HIDDEN / BK)         // 16 K-tiles
#define ABYTES (BM * BK * 2)     // 32768
#define BBYTES (BN * BK * 2)     // 40960
#define BUFSZ  (ABYTES + BBYTES) // 73728
// LDS = 2 * 73728 = 147456 (1 block/CU)

typedef float  f32x4  __attribute__((ext_vector_type(4)));
typedef __bf16 bf16x8 __attribute__((ext_vector_type(8)));
typedef __bf16 bf16x4 __attribute__((ext_vector_type(4)));

__device__ __forceinline__ void gload_lds16(const void* g, void* l) {
    __builtin_amdgcn_global_load_lds(
        (const __attribute__((address_space(1))) unsigned int*)g,
        (__attribute__((address_space(3))) unsigned int*)l, 16, 0, 0);
}
// Swizzle: logical byte x (128B rows) lives at x ^ ((row&7)<<4). Involution.
__device__ __forceinline__ unsigned swz(unsigned x) {
    return x ^ (((x >> 7) & 7u) << 4);
}

// ---------------------------------------------------------------------------
// Pass 1a: x f32 -> bf16
// ---------------------------------------------------------------------------
__global__ __launch_bounds__(256)
void cvt_x(const float* __restrict__ x, __bf16* __restrict__ xc, int n8)
{
    int idx = blockIdx.x * blockDim.x + threadIdx.x;
    int stride = gridDim.x * blockDim.x;
    for (int i = idx; i < n8; i += stride) {
        const float4 a = *reinterpret_cast<const float4*>(x + (size_t)i * 8);
        const float4 b = *reinterpret_cast<const float4*>(x + (size_t)i * 8 + 4);
        bf16x8 h;
        h[0] = (__bf16)a.x; h[1] = (__bf16)a.y; h[2] = (__bf16)a.z; h[3] = (__bf16)a.w;
        h[4] = (__bf16)b.x; h[5] = (__bf16)b.y; h[6] = (__bf16)b.z; h[7] = (__bf16)b.w;
        *reinterpret_cast<bf16x8*>(xc + (size_t)i * 8) = h;
    }
}

// ---------------------------------------------------------------------------
// Pass 1b: W f32 [K][N] -> Wt bf16 [N][K]
// ---------------------------------------------------------------------------
__global__ __launch_bounds__(256)
void cvt_w(const float* __restrict__ W, __bf16* __restrict__ Wt)
{
    __shared__ __bf16 tile[64][72];
    const int t  = threadIdx.x;
    const int n0 = blockIdx.x * 64;
    const int k0 = blockIdx.y * 64;

    #pragma unroll
    for (int i = 0; i < 4; ++i) {
        const int k    = (t >> 4) + i * 16;
        const int col4 = (t & 15) * 4;
        const float4 v = *reinterpret_cast<const float4*>(
            W + (size_t)(k0 + k) * HEADS + n0 + col4);
        bf16x4 h;
        h[0] = (__bf16)v.x; h[1] = (__bf16)v.y; h[2] = (__bf16)v.z; h[3] = (__bf16)v.w;
        *reinterpret_cast<bf16x4*>(&tile[k][col4]) = h;
    }
    __syncthreads();
    #pragma unroll
    for (int i = 0; i < 4; ++i) {
        const int n  = (t >> 4) + i * 16;
        const int k4 = (t & 15) * 4;
        bf16x4 h;
        h[0] = tile[k4 + 0][n]; h[1] = tile[k4 + 1][n];
        h[2] = tile[k4 + 2][n]; h[3] = tile[k4 + 3][n];
        *reinterpret_cast<bf16x4*>(Wt + (size_t)(n0 + n) * HIDDEN + k0 + k4) = h;
    }
}

// ---------------------------------------------------------------------------
// Pass 2: de-lockstepped pipeline. 256x320 tile, 8 waves (2M x 4N), per-wave
// 128x80 = acc[8][5]. Per K-tile: {issue 9 gload_lds for tile k+1 (early) |
// 26 ds_read + 80 MFMA, compiler-scheduled fine-grained lgkmcnt | vmcnt(0)
// (covered by a full tile of compute) | one s_barrier}. No intra-tile
// barriers: phases read an already-complete buffer; the staged-into buffer's
// readers finished before the previous tile-boundary barrier.
// ---------------------------------------------------------------------------
__global__ __launch_bounds__(512, 2)
void gemm_dl(const __bf16* __restrict__ A, const __bf16* __restrict__ Bt,
             const float* __restrict__ bias, float* __restrict__ out)
{
    __shared__ char lds[2 * BUFSZ];

    const int t    = threadIdx.x;
    const int lane = t & 63;
    const int w    = t >> 6;      // 0..7
    const int wr   = w >> 2;      // 0..1 : 128-row slab
    const int wc   = w & 3;       // 0..3 : 80-col slab
    const int lhi  = lane >> 4;   // 0..3
    const int llo  = lane & 15;   // 0..15

    // by = bid&7 == XCD id: each XCD's 32 blocks share one 640KB B-panel in L2
    const int by  = blockIdx.x & 7;
    const int bx  = blockIdx.x >> 3;
    const int bm0 = bx * BM;
    const int bn0 = by * BN;

    // ---- stage descriptors. d = li*8192 + t*16; row&7 is li-invariant, so
    // swz offset within the row is li-invariant: src[li] = src0 + li*131072.
    const unsigned d0 = (unsigned)(t * 16);
    const unsigned L0 = swz(d0);
    const char* asrc0 = (const char*)A  + (size_t)(bm0 + (L0 >> 7)) * (HIDDEN * 2) + (L0 & 127);
    const char* bsrc0 = (const char*)Bt + (size_t)(bn0 + (L0 >> 7)) * (HIDDEN * 2) + (L0 & 127);
    char* adst0 = (char*)lds + d0;
    char* bdst0 = (char*)lds + ABYTES + d0;

    // ---- fragment read offsets; row&7 == llo&7 for both A and B slabs
    const unsigned xa   = (unsigned)((llo & 7) << 4);
    const unsigned klo0 = ((unsigned)(lhi * 16)) ^ xa;        // kk = 0
    const unsigned klo1 = ((unsigned)(64 + lhi * 16)) ^ xa;   // kk = 1
    unsigned offA[8], offB[5];
    #pragma unroll
    for (int m = 0; m < 8; ++m)
        offA[m] = (unsigned)((wr * 128 + m * 16 + llo) * 128);
    #pragma unroll
    for (int n = 0; n < 5; ++n)
        offB[n] = (unsigned)ABYTES + (unsigned)((wc * 80 + n * 16 + llo) * 128);

    f32x4 acc[8][5];
    #pragma unroll
    for (int m = 0; m < 8; ++m)
        #pragma unroll
        for (int n = 0; n < 5; ++n)
            acc[m][n] = f32x4{0.f, 0.f, 0.f, 0.f};

    // ---- prologue: stage T0 -> buf0
    #pragma unroll
    for (int li = 0; li < 4; ++li) gload_lds16(asrc0 + li * 131072, adst0 + li * 8192);
    #pragma unroll
    for (int li = 0; li < 5; ++li) gload_lds16(bsrc0 + li * 131072, bdst0 + li * 8192);
    asm volatile("s_waitcnt vmcnt(0)" ::: "memory");
    __builtin_amdgcn_s_barrier();

    for (int k = 0; k < NT; ++k) {
        const char* buf  = lds + (k & 1) * BUFSZ;
        const unsigned nb = (unsigned)(((k + 1) & 1) * BUFSZ);
        const int   koff = (k + 1) * 128;

        // ---- early issue: stage tile k+1 (full tile of latency cover)
        if (k + 1 < NT) {
            #pragma unroll
            for (int li = 0; li < 4; ++li)
                gload_lds16(asrc0 + li * 131072 + koff, adst0 + nb + li * 8192);
            #pragma unroll
            for (int li = 0; li < 5; ++li)
                gload_lds16(bsrc0 + li * 131072 + koff, bdst0 + nb + li * 8192);
        }

        // ---- compute: compiler interleaves ds_read with MFMA (fine lgkmcnt)
        {
            bf16x8 af[8], bfr[5];
            #pragma unroll
            for (int m = 0; m < 8; ++m) af[m]  = *(const bf16x8*)(buf + (offA[m] + klo0));
            #pragma unroll
            for (int n = 0; n < 5; ++n) bfr[n] = *(const bf16x8*)(buf + (offB[n] + klo0));
            #pragma unroll
            for (int m = 0; m < 8; ++m)
                #pragma unroll
                for (int n = 0; n < 5; ++n)
                    acc[m][n] = __builtin_amdgcn_mfma_f32_16x16x32_bf16(
                        af[m], bfr[n], acc[m][n], 0, 0, 0);
        }
        {
            bf16x8 af[8], bfr[5];
            #pragma unroll
            for (int m = 0; m < 8; ++m) af[m]  = *(const bf16x8*)(buf + (offA[m] + klo1));
            #pragma unroll
            for (int n = 0; n < 5; ++n) bfr[n] = *(const bf16x8*)(buf + (offB[n] + klo1));
            #pragma unroll
            for (int m = 0; m < 8; ++m)
                #pragma unroll
                for (int n = 0; n < 5; ++n)
                    acc[m][n] = __builtin_amdgcn_mfma_f32_16x16x32_bf16(
                        af[m], bfr[n], acc[m][n], 0, 0, 0);
        }

        // ---- tile boundary: staged loads had the whole tile to land
        asm volatile("s_waitcnt vmcnt(0)" ::: "memory");
        __builtin_amdgcn_s_barrier();
    }

    // ---- epilogue: bias + sigmoid; C/D: col = lane&15, row = (lane>>4)*4+reg
    #pragma unroll
    for (int n = 0; n < 5; ++n) {
        const int col  = bn0 + wc * 80 + n * 16 + llo;
        const float bv = bias[col];
        #pragma unroll
        for (int m = 0; m < 8; ++m) {
            const int row0 = bm0 + wr * 128 + m * 16 + lhi * 4;
            #pragma unroll
            for (int r = 0; r < 4; ++r) {
                const float z = acc[m][n][r] + bv;
                out[(size_t)(row0 + r) * HEADS + col] = __fdividef(1.0f, 1.0f + __expf(-z));
            }
        }
    }
}

// ---------------------------------------------------------------------------
// Fallback (R1 fused kernel) if workspace is too small.
// ---------------------------------------------------------------------------
#define FBM 128
#define FBN 128
#define FBK 32
#define FLDK 40

__global__ __launch_bounds__(256)
void lch_gemm(const float* __restrict__ x, const float* __restrict__ W,
              const float* __restrict__ b, float* __restrict__ out)
{
    __shared__ __bf16 As[FBM][FLDK];
    __shared__ __bf16 Bs[FBN][FLDK];

    const int t   = threadIdx.x;
    const int bm0 = blockIdx.x * FBM;
    const int bn0 = blockIdx.y * FBN;
    const int lane = t & 63;
    const int wid  = t >> 6;
    const int wr   = wid >> 1;
    const int wc   = wid & 1;
    const int lhi  = lane >> 4;
    const int llo  = lane & 15;

    f32x4 acc[4][4];
    #pragma unroll
    for (int i = 0; i < 4; ++i)
        #pragma unroll
        for (int j = 0; j < 4; ++j)
            acc[i][j] = f32x4{0.f, 0.f, 0.f, 0.f};

    const int bn_col  = t & 127;
    const int bk_base = (t >> 7) * 16;

    for (int k0 = 0; k0 < HIDDEN; k0 += FBK) {
        #pragma unroll
        for (int i = 0; i < 4; ++i) {
            const int f   = t + i * 256;
            const int row = f >> 3;
            const int c4  = (f & 7) * 4;
            const float4 v = *reinterpret_cast<const float4*>(
                x + (size_t)(bm0 + row) * HIDDEN + k0 + c4);
            bf16x4 h;
            h[0] = (__bf16)v.x; h[1] = (__bf16)v.y;
            h[2] = (__bf16)v.z; h[3] = (__bf16)v.w;
            *reinterpret_cast<bf16x4*>(&As[row][c4]) = h;
        }
        {
            const float* wp = W + (size_t)(k0 + bk_base) * HEADS + bn0 + bn_col;
            bf16x8 h0, h1;
            #pragma unroll
            for (int i = 0; i < 8; ++i) h0[i] = (__bf16)wp[(size_t)i * HEADS];
            #pragma unroll
            for (int i = 0; i < 8; ++i) h1[i] = (__bf16)wp[(size_t)(i + 8) * HEADS];
            *reinterpret_cast<bf16x8*>(&Bs[bn_col][bk_base])     = h0;
            *reinterpret_cast<bf16x8*>(&Bs[bn_col][bk_base + 8]) = h1;
        }
        __syncthreads();

        bf16x8 af[4], bfr[4];
        #pragma unroll
        for (int i = 0; i < 4; ++i)
            af[i] = *reinterpret_cast<const bf16x8*>(&As[wr * 64 + i * 16 + llo][lhi * 8]);
        #pragma unroll
        for (int j = 0; j < 4; ++j)
            bfr[j] = *reinterpret_cast<const bf16x8*>(&Bs[wc * 64 + j * 16 + llo][lhi * 8]);
        #pragma unroll
        for (int i = 0; i < 4; ++i)
            #pragma unroll
            for (int j = 0; j < 4; ++j)
                acc[i][j] = __builtin_amdgcn_mfma_f32_16x16x32_bf16(
                    af[i], bfr[j], acc[i][j], 0, 0, 0);
        __syncthreads();
    }

    #pragma unroll
    for (int j = 0; j < 4; ++j) {
        const int col  = bn0 + wc * 64 + j * 16 + llo;
        const float bv = b[col];
        #pragma unroll
        for (int i = 0; i < 4; ++i) {
            const int row0 = bm0 + wr * 64 + i * 16 + lhi * 4;
            #pragma unroll
            for (int r = 0; r < 4; ++r) {
                const float z = acc[i][j][r] + bv;
                out[(size_t)(row0 + r) * HEADS + col] = 1.0f / (1.0f + __expf(-z));
            }
        }
    }
}

extern "C" void kernel_launch(void* const* d_in, const int* in_sizes, int n_in,
                              void* d_out, int out_size, void* d_ws, size_t ws_size,
                              hipStream_t stream) {
    const float* x = (const float*)d_in[0];
    const float* W = (const float*)d_in[1];
    const float* b = (const float*)d_in[2];
    float* out     = (float*)d_out;

    const int M = in_sizes[0] / HIDDEN;   // 8192

    const size_t xc_bytes = (size_t)M * HIDDEN * sizeof(__bf16);
    const size_t wt_bytes = (size_t)HEADS * HIDDEN * sizeof(__bf16);

    if (ws_size >= xc_bytes + wt_bytes && (M % BM) == 0) {
        __bf16* xc = (__bf16*)d_ws;
        __bf16* Wt = (__bf16*)((char*)d_ws + xc_bytes);

        cvt_x<<<2048, 256, 0, stream>>>(x, xc, M * HIDDEN / 8);
        cvt_w<<<dim3(HEADS / 64, HIDDEN / 64), 256, 0, stream>>>(W, Wt);

        const int nwg = (M / BM) * (HEADS / BN);   // 32 * 8 = 256
        gemm_dl<<<nwg, 512, 0, stream>>>(xc, Wt, b, out);
    } else {
        dim3 grid(M / FBM, HEADS / FBN);
        lch_gemm<<<grid, dim3(256), 0, stream>>>(x, W, b, out);
    }
}

// Round 7
// 66.844 us; speedup vs baseline: 1.4580x; 1.0025x over previous
//
#include <hip/hip_runtime.h>
#include <hip/hip_bf16.h>

#define HIDDEN 1024
#define HEADS  2560

// GEMM geometry: 128x160 tile, BK=64, grid = (8192/128)*(2560/160) = 64*16 = 1024
// LDS: 2 buffers * (16384 + 20480) = 73728 B -> 2 blocks/CU, 16 waves/CU.
#define BM 128
#define BN 160
#define BK 64
#define NT (HIDDEN / BK)        // 16 K-tiles
#define ABYT (BM * BK * 2)      // 16384
#define BBYT (BN * BK * 2)      // 20480
#define BUFSZ (ABYT + BBYT)     // 36864

typedef float  f32x4  __attribute__((ext_vector_type(4)));
typedef __bf16 bf16x8 __attribute__((ext_vector_type(8)));
typedef __bf16 bf16x4 __attribute__((ext_vector_type(4)));

__device__ __forceinline__ void gload_lds16(const void* g, void* l) {
    __builtin_amdgcn_global_load_lds(
        (const __attribute__((address_space(1))) unsigned int*)g,
        (__attribute__((address_space(3))) unsigned int*)l, 16, 0, 0);
}
// Swizzle: logical byte x (128B rows) lives at x ^ ((row&7)<<4). Involution.
__device__ __forceinline__ unsigned swz(unsigned x) {
    return x ^ (((x >> 7) & 7u) << 4);
}

// ---------------------------------------------------------------------------
// Fused pass 1: blocks [0,640) transpose W f32[K][N] -> Wt bf16[N][K];
//               blocks [640,...) convert x f32 -> bf16.
// ---------------------------------------------------------------------------
__global__ __launch_bounds__(256)
void cvt_all(const float* __restrict__ x, const float* __restrict__ W,
             __bf16* __restrict__ xc, __bf16* __restrict__ Wt, int n8)
{
    if (blockIdx.x < 640) {
        __shared__ __bf16 tile[64][72];
        const int t  = threadIdx.x;
        const int n0 = (blockIdx.x % 40) * 64;
        const int k0 = (blockIdx.x / 40) * 64;

        #pragma unroll
        for (int i = 0; i < 4; ++i) {
            const int k    = (t >> 4) + i * 16;
            const int col4 = (t & 15) * 4;
            const float4 v = *reinterpret_cast<const float4*>(
                W + (size_t)(k0 + k) * HEADS + n0 + col4);
            bf16x4 h;
            h[0] = (__bf16)v.x; h[1] = (__bf16)v.y; h[2] = (__bf16)v.z; h[3] = (__bf16)v.w;
            *reinterpret_cast<bf16x4*>(&tile[k][col4]) = h;
        }
        __syncthreads();
        #pragma unroll
        for (int i = 0; i < 4; ++i) {
            const int n  = (t >> 4) + i * 16;
            const int k4 = (t & 15) * 4;
            bf16x4 h;
            h[0] = tile[k4 + 0][n]; h[1] = tile[k4 + 1][n];
            h[2] = tile[k4 + 2][n]; h[3] = tile[k4 + 3][n];
            *reinterpret_cast<bf16x4*>(Wt + (size_t)(n0 + n) * HIDDEN + k0 + k4) = h;
        }
    } else {
        int idx    = (blockIdx.x - 640) * blockDim.x + threadIdx.x;
        int stride = (gridDim.x - 640) * blockDim.x;
        for (int i = idx; i < n8; i += stride) {
            const float4 a = *reinterpret_cast<const float4*>(x + (size_t)i * 8);
            const float4 b = *reinterpret_cast<const float4*>(x + (size_t)i * 8 + 4);
            bf16x8 h;
            h[0] = (__bf16)a.x; h[1] = (__bf16)a.y; h[2] = (__bf16)a.z; h[3] = (__bf16)a.w;
            h[4] = (__bf16)b.x; h[5] = (__bf16)b.y; h[6] = (__bf16)b.z; h[7] = (__bf16)b.w;
            *reinterpret_cast<bf16x8*>(xc + (size_t)i * 8) = h;
        }
    }
}

// ---------------------------------------------------------------------------
// Pass 2: 128x160 tile, 8 waves (4M x 2N), per-wave 32x80 = acc[2][5].
// Delockstep schedule: per K-tile {issue staging for k+1 | ds_read+MFMA
// (compiler fine-grained lgkmcnt) | vmcnt(0) covered by full tile | barrier}.
// 2 blocks/CU: co-resident block's MFMA overlaps this block's epilogue writes.
// ---------------------------------------------------------------------------
__global__ __launch_bounds__(512, 4)
void gemm_dl2(const __bf16* __restrict__ A, const __bf16* __restrict__ Bt,
              const float* __restrict__ bias, float* __restrict__ out)
{
    __shared__ char lds[2 * BUFSZ];

    const int t    = threadIdx.x;
    const int lane = t & 63;
    const int w    = t >> 6;      // 0..7
    const int wr   = w & 3;       // 0..3 : 32-row slab
    const int wc   = w >> 2;      // 0..1 : 80-col slab
    const int lhi  = lane >> 4;   // 0..3
    const int llo  = lane & 15;   // 0..15

    // XCD mapping: XCD(bid)=bid%8 gets by in {2i,2i+1} -> 2 B-panels (640KB) per L2
    const int bid = blockIdx.x;
    const int by  = (bid & 7) * 2 + ((bid >> 3) & 1);
    const int bx  = bid >> 4;
    const int bm0 = bx * BM;
    const int bn0 = by * BN;

    // ---- staging descriptors. Region byte d -> physical L=swz(d): row=L>>7,
    // col=L&127. Advancing d by 8192 adds 64 rows ((row&7) unchanged) ->
    // src advance is uniform 64*2048 = 131072 bytes.
    const unsigned d0 = (unsigned)(t * 16);
    const unsigned L0 = swz(d0);
    const char* asrc0 = (const char*)A  + (size_t)(bm0 + (L0 >> 7)) * (HIDDEN * 2) + (L0 & 127);
    const char* bsrc0 = (const char*)Bt + (size_t)(bn0 + (L0 >> 7)) * (HIDDEN * 2) + (L0 & 127);
    // B tail: bytes [16384, 20480) of B region, staged by waves 0-3 (t<256)
    const unsigned dt = 16384u + (unsigned)(t * 16);
    const unsigned Lt = swz(dt);
    const char* bsrct = (const char*)Bt + (size_t)(bn0 + (Lt >> 7)) * (HIDDEN * 2) + (Lt & 127);

    char* adst0 = (char*)lds + d0;               // A region [0, 16384)
    char* bdst0 = (char*)lds + ABYT + d0;        // B region [16384, 36864)
    char* bdstt = (char*)lds + ABYT + dt;

    // ---- fragment read offsets. Physical within-row offset for logical
    // (kk*64 + lhi*16) in a row with row&7 == llo&7. XOR FOLDED BEFORE any
    // add: klo[kk] < 128, so rowbase + klo[kk] never carries into row bits.
    // (R6 bug: klo0 + kk*64 carried into bit 7 when xa had bit 6 set.)
    const unsigned xa = (unsigned)((llo & 7) << 4);
    const unsigned klo[2] = { ((unsigned)(lhi * 16)) ^ xa,
                              ((unsigned)(64 + lhi * 16)) ^ xa };
    const unsigned rowA = (unsigned)((wr * 32 + llo) * 128);
    const unsigned rowB = (unsigned)ABYT + (unsigned)((wc * 80 + llo) * 128);

    f32x4 acc[2][5];
    #pragma unroll
    for (int m = 0; m < 2; ++m)
        #pragma unroll
        for (int n = 0; n < 5; ++n)
            acc[m][n] = f32x4{0.f, 0.f, 0.f, 0.f};

    // ---- prologue: stage T0 -> buf0
    gload_lds16(asrc0,          adst0);
    gload_lds16(asrc0 + 131072, adst0 + 8192);
    gload_lds16(bsrc0,          bdst0);
    gload_lds16(bsrc0 + 131072, bdst0 + 8192);
    if (w < 4) gload_lds16(bsrct, bdstt);
    asm volatile("s_waitcnt vmcnt(0)" ::: "memory");
    __builtin_amdgcn_s_barrier();

    for (int k = 0; k < NT; ++k) {
        const char* buf  = lds + (k & 1) * BUFSZ;
        const unsigned nb = (unsigned)(((k + 1) & 1) * BUFSZ);
        const int   koff = (k + 1) * 128;   // byte advance into next K-tile

        // ---- early issue: stage tile k+1 (a full tile of latency cover)
        if (k + 1 < NT) {
            gload_lds16(asrc0 + koff,          adst0 + nb);
            gload_lds16(asrc0 + koff + 131072, adst0 + nb + 8192);
            gload_lds16(bsrc0 + koff,          bdst0 + nb);
            gload_lds16(bsrc0 + koff + 131072, bdst0 + nb + 8192);
            if (w < 4) gload_lds16(bsrct + koff, bdstt + nb);
        }

        // ---- compute: 14 ds_read_b128 + 20 MFMA, compiler-scheduled
        #pragma unroll
        for (int kk = 0; kk < 2; ++kk) {
            bf16x8 af[2], bfr[5];
            #pragma unroll
            for (int m = 0; m < 2; ++m)
                af[m]  = *(const bf16x8*)(buf + rowA + m * 2048 + klo[kk]);
            #pragma unroll
            for (int n = 0; n < 5; ++n)
                bfr[n] = *(const bf16x8*)(buf + rowB + n * 2048 + klo[kk]);
            #pragma unroll
            for (int m = 0; m < 2; ++m)
                #pragma unroll
                for (int n = 0; n < 5; ++n)
                    acc[m][n] = __builtin_amdgcn_mfma_f32_16x16x32_bf16(
                        af[m], bfr[n], acc[m][n], 0, 0, 0);
        }

        // ---- tile boundary
        asm volatile("s_waitcnt vmcnt(0)" ::: "memory");
        __builtin_amdgcn_s_barrier();
    }

    // ---- epilogue: bias + sigmoid; C/D: col = lane&15, row = (lane>>4)*4+reg
    #pragma unroll
    for (int n = 0; n < 5; ++n) {
        const int col  = bn0 + wc * 80 + n * 16 + llo;
        const float bv = bias[col];
        #pragma unroll
        for (int m = 0; m < 2; ++m) {
            const int row0 = bm0 + wr * 32 + m * 16 + lhi * 4;
            #pragma unroll
            for (int r = 0; r < 4; ++r) {
                const float z = acc[m][n][r] + bv;
                out[(size_t)(row0 + r) * HEADS + col] = __fdividef(1.0f, 1.0f + __expf(-z));
            }
        }
    }
}

// ---------------------------------------------------------------------------
// Fallback (R1 fused kernel) if workspace is too small.
// ---------------------------------------------------------------------------
#define FBM 128
#define FBN 128
#define FBK 32
#define FLDK 40

__global__ __launch_bounds__(256)
void lch_gemm(const float* __restrict__ x, const float* __restrict__ W,
              const float* __restrict__ b, float* __restrict__ out)
{
    __shared__ __bf16 As[FBM][FLDK];
    __shared__ __bf16 Bs[FBN][FLDK];

    const int t   = threadIdx.x;
    const int bm0 = blockIdx.x * FBM;
    const int bn0 = blockIdx.y * FBN;
    const int lane = t & 63;
    const int wid  = t >> 6;
    const int wr   = wid >> 1;
    const int wc   = wid & 1;
    const int lhi  = lane >> 4;
    const int llo  = lane & 15;

    f32x4 acc[4][4];
    #pragma unroll
    for (int i = 0; i < 4; ++i)
        #pragma unroll
        for (int j = 0; j < 4; ++j)
            acc[i][j] = f32x4{0.f, 0.f, 0.f, 0.f};

    const int bn_col  = t & 127;
    const int bk_base = (t >> 7) * 16;

    for (int k0 = 0; k0 < HIDDEN; k0 += FBK) {
        #pragma unroll
        for (int i = 0; i < 4; ++i) {
            const int f   = t + i * 256;
            const int row = f >> 3;
            const int c4  = (f & 7) * 4;
            const float4 v = *reinterpret_cast<const float4*>(
                x + (size_t)(bm0 + row) * HIDDEN + k0 + c4);
            bf16x4 h;
            h[0] = (__bf16)v.x; h[1] = (__bf16)v.y;
            h[2] = (__bf16)v.z; h[3] = (__bf16)v.w;
            *reinterpret_cast<bf16x4*>(&As[row][c4]) = h;
        }
        {
            const float* wp = W + (size_t)(k0 + bk_base) * HEADS + bn0 + bn_col;
            bf16x8 h0, h1;
            #pragma unroll
            for (int i = 0; i < 8; ++i) h0[i] = (__bf16)wp[(size_t)i * HEADS];
            #pragma unroll
            for (int i = 0; i < 8; ++i) h1[i] = (__bf16)wp[(size_t)(i + 8) * HEADS];
            *reinterpret_cast<bf16x8*>(&Bs[bn_col][bk_base])     = h0;
            *reinterpret_cast<bf16x8*>(&Bs[bn_col][bk_base + 8]) = h1;
        }
        __syncthreads();

        bf16x8 af[4], bfr[4];
        #pragma unroll
        for (int i = 0; i < 4; ++i)
            af[i] = *reinterpret_cast<const bf16x8*>(&As[wr * 64 + i * 16 + llo][lhi * 8]);
        #pragma unroll
        for (int j = 0; j < 4; ++j)
            bfr[j] = *reinterpret_cast<const bf16x8*>(&Bs[wc * 64 + j * 16 + llo][lhi * 8]);
        #pragma unroll
        for (int i = 0; i < 4; ++i)
            #pragma unroll
            for (int j = 0; j < 4; ++j)
                acc[i][j] = __builtin_amdgcn_mfma_f32_16x16x32_bf16(
                    af[i], bfr[j], acc[i][j], 0, 0, 0);
        __syncthreads();
    }

    #pragma unroll
    for (int j = 0; j < 4; ++j) {
        const int col  = bn0 + wc * 64 + j * 16 + llo;
        const float bv = b[col];
        #pragma unroll
        for (int i = 0; i < 4; ++i) {
            const int row0 = bm0 + wr * 64 + i * 16 + lhi * 4;
            #pragma unroll
            for (int r = 0; r < 4; ++r) {
                const float z = acc[i][j][r] + bv;
                out[(size_t)(row0 + r) * HEADS + col] = 1.0f / (1.0f + __expf(-z));
            }
        }
    }
}

extern "C" void kernel_launch(void* const* d_in, const int* in_sizes, int n_in,
                              void* d_out, int out_size, void* d_ws, size_t ws_size,
                              hipStream_t stream) {
    const float* x = (const float*)d_in[0];
    const float* W = (const float*)d_in[1];
    const float* b = (const float*)d_in[2];
    float* out     = (float*)d_out;

    const int M = in_sizes[0] / HIDDEN;   // 8192

    const size_t xc_bytes = (size_t)M * HIDDEN * sizeof(__bf16);
    const size_t wt_bytes = (size_t)HEADS * HIDDEN * sizeof(__bf16);

    if (ws_size >= xc_bytes + wt_bytes && (M % BM) == 0) {
        __bf16* xc = (__bf16*)d_ws;
        __bf16* Wt = (__bf16*)((char*)d_ws + xc_bytes);

        cvt_all<<<640 + 2048, 256, 0, stream>>>(x, W, xc, Wt, M * HIDDEN / 8);

        const int nwg = (M / BM) * (HEADS / BN);   // 64 * 16 = 1024
        gemm_dl2<<<nwg, 512, 0, stream>>>(xc, Wt, b, out);
    } else {
        dim3 grid(M / FBM, HEADS / FBN);
        lch_gemm<<<grid, dim3(256), 0, stream>>>(x, W, b, out);
    }
}

// Round 8
// 65.302 us; speedup vs baseline: 1.4925x; 1.0236x over previous
//
#include <hip/hip_runtime.h>
#include <hip/hip_bf16.h>

#define HIDDEN 1024
#define HEADS  2560

// GEMM geometry: 256x320 tile, BK=64, grid = (8192/256)*(2560/320) = 32*8 = 256
// = 1 block/CU. 8 waves (2M x 4N), per-wave 128x80 = acc[8][5]:
// fragment-traffic ratio (8+5)/(8*5) = 0.325 -> LDS pipe ~ MFMA pipe (balanced).
#define BM 256
#define BN 320
#define BK 64
#define NT (HIDDEN / BK)        // 16 K-tiles
#define ABYT (BM * BK * 2)      // 32768
#define BBYT (BN * BK * 2)      // 40960
#define BUFSZ (ABYT + BBYT)     // 73728 ; dbuf = 147456

typedef float  f32x4  __attribute__((ext_vector_type(4)));
typedef __bf16 bf16x8 __attribute__((ext_vector_type(8)));
typedef __bf16 bf16x4 __attribute__((ext_vector_type(4)));

__device__ __forceinline__ void gload_lds16(const void* g, void* l) {
    __builtin_amdgcn_global_load_lds(
        (const __attribute__((address_space(1))) unsigned int*)g,
        (__attribute__((address_space(3))) unsigned int*)l, 16, 0, 0);
}
// Swizzle: logical byte x (128B rows) lives at x ^ ((row&7)<<4). Involution.
__device__ __forceinline__ unsigned swz(unsigned x) {
    return x ^ (((x >> 7) & 7u) << 4);
}

// ---------------------------------------------------------------------------
// Fused pass 1: blocks [0,640) transpose W f32[K][N] -> Wt bf16[N][K];
//               blocks [640,...) convert x f32 -> bf16.
// ---------------------------------------------------------------------------
__global__ __launch_bounds__(256)
void cvt_all(const float* __restrict__ x, const float* __restrict__ W,
             __bf16* __restrict__ xc, __bf16* __restrict__ Wt, int n8)
{
    if (blockIdx.x < 640) {
        __shared__ __bf16 tile[64][72];
        const int t  = threadIdx.x;
        const int n0 = (blockIdx.x % 40) * 64;
        const int k0 = (blockIdx.x / 40) * 64;

        #pragma unroll
        for (int i = 0; i < 4; ++i) {
            const int k    = (t >> 4) + i * 16;
            const int col4 = (t & 15) * 4;
            const float4 v = *reinterpret_cast<const float4*>(
                W + (size_t)(k0 + k) * HEADS + n0 + col4);
            bf16x4 h;
            h[0] = (__bf16)v.x; h[1] = (__bf16)v.y; h[2] = (__bf16)v.z; h[3] = (__bf16)v.w;
            *reinterpret_cast<bf16x4*>(&tile[k][col4]) = h;
        }
        __syncthreads();
        #pragma unroll
        for (int i = 0; i < 4; ++i) {
            const int n  = (t >> 4) + i * 16;
            const int k4 = (t & 15) * 4;
            bf16x4 h;
            h[0] = tile[k4 + 0][n]; h[1] = tile[k4 + 1][n];
            h[2] = tile[k4 + 2][n]; h[3] = tile[k4 + 3][n];
            *reinterpret_cast<bf16x4*>(Wt + (size_t)(n0 + n) * HIDDEN + k0 + k4) = h;
        }
    } else {
        int idx    = (blockIdx.x - 640) * blockDim.x + threadIdx.x;
        int stride = (gridDim.x - 640) * blockDim.x;
        for (int i = idx; i < n8; i += stride) {
            const float4 a = *reinterpret_cast<const float4*>(x + (size_t)i * 8);
            const float4 b = *reinterpret_cast<const float4*>(x + (size_t)i * 8 + 4);
            bf16x8 h;
            h[0] = (__bf16)a.x; h[1] = (__bf16)a.y; h[2] = (__bf16)a.z; h[3] = (__bf16)a.w;
            h[4] = (__bf16)b.x; h[5] = (__bf16)b.y; h[6] = (__bf16)b.z; h[7] = (__bf16)b.w;
            *reinterpret_cast<bf16x8*>(xc + (size_t)i * 8) = h;
        }
    }
}

// ---------------------------------------------------------------------------
// Pass 2: R4 geometry x R7 schedule. Per K-tile: {issue 9 gload_lds for k+1 |
// 26 ds_read_b128 + 80 MFMA per wave (compiler fine-grained lgkmcnt; waves
// skew freely -- no intra-tile barriers) | vmcnt(0) covered by full tile |
// one s_barrier}. setprio(1) around MFMA clusters (waves at distinct phases).
// ---------------------------------------------------------------------------
__global__ __launch_bounds__(512, 2)
void gemm_big(const __bf16* __restrict__ A, const __bf16* __restrict__ Bt,
              const float* __restrict__ bias, float* __restrict__ out)
{
    __shared__ char lds[2 * BUFSZ];

    const int t    = threadIdx.x;
    const int lane = t & 63;
    const int w    = t >> 6;      // 0..7
    const int wr   = w >> 2;      // 0..1 : 128-row slab
    const int wc   = w & 3;       // 0..3 : 80-col slab
    const int lhi  = lane >> 4;   // 0..3
    const int llo  = lane & 15;   // 0..15

    // by = bid&7 == XCD id: each XCD's 32 blocks share ONE 640KB B-panel in L2
    const int bid = blockIdx.x;
    const int by  = bid & 7;
    const int bx  = bid >> 3;
    const int bm0 = bx * BM;
    const int bn0 = by * BN;

    // ---- staging descriptors. Region byte d = li*8192 + t*16; row&7 = (t>>3)&7
    // is li-invariant -> per-li source advance is uniform 64*2048 = 131072 B.
    const unsigned d0 = (unsigned)(t * 16);
    const unsigned L0 = swz(d0);
    const char* asrc0 = (const char*)A  + (size_t)(bm0 + (L0 >> 7)) * (HIDDEN * 2) + (L0 & 127);
    const char* bsrc0 = (const char*)Bt + (size_t)(bn0 + (L0 >> 7)) * (HIDDEN * 2) + (L0 & 127);
    char* adst0 = (char*)lds + d0;          // A region [0, 32768)
    char* bdst0 = (char*)lds + ABYT + d0;   // B region [32768, 73728)

    // ---- fragment read offsets; XOR folded BEFORE any add (klo < 128: no
    // carry into row bits -- the R6 bug). row&7 == llo&7 for A and B slabs.
    const unsigned xa = (unsigned)((llo & 7) << 4);
    const unsigned klo[2] = { ((unsigned)(lhi * 16)) ^ xa,
                              ((unsigned)(64 + lhi * 16)) ^ xa };
    const unsigned rowA = (unsigned)(wr * 16384 + llo * 128);
    const unsigned rowB = (unsigned)ABYT + (unsigned)(wc * 10240 + llo * 128);

    f32x4 acc[8][5];
    #pragma unroll
    for (int m = 0; m < 8; ++m)
        #pragma unroll
        for (int n = 0; n < 5; ++n)
            acc[m][n] = f32x4{0.f, 0.f, 0.f, 0.f};

    // ---- prologue: stage T0 -> buf0
    #pragma unroll
    for (int li = 0; li < 4; ++li) gload_lds16(asrc0 + li * 131072, adst0 + li * 8192);
    #pragma unroll
    for (int li = 0; li < 5; ++li) gload_lds16(bsrc0 + li * 131072, bdst0 + li * 8192);
    asm volatile("s_waitcnt vmcnt(0)" ::: "memory");
    __builtin_amdgcn_s_barrier();

    for (int k = 0; k < NT; ++k) {
        const char* buf  = lds + (k & 1) * BUFSZ;
        const unsigned nb = (unsigned)(((k + 1) & 1) * BUFSZ);
        const int   koff = (k + 1) * 128;   // byte advance into next K-tile

        // ---- early issue: stage tile k+1 (a full tile of latency cover)
        if (k + 1 < NT) {
            #pragma unroll
            for (int li = 0; li < 4; ++li)
                gload_lds16(asrc0 + koff + li * 131072, adst0 + nb + li * 8192);
            #pragma unroll
            for (int li = 0; li < 5; ++li)
                gload_lds16(bsrc0 + koff + li * 131072, bdst0 + nb + li * 8192);
        }

        // ---- compute: 2 x {13 ds_read_b128 + 40 MFMA}, compiler-scheduled
        #pragma unroll
        for (int kk = 0; kk < 2; ++kk) {
            bf16x8 af[8], bfr[5];
            #pragma unroll
            for (int m = 0; m < 8; ++m)
                af[m]  = *(const bf16x8*)(buf + rowA + m * 2048 + klo[kk]);
            #pragma unroll
            for (int n = 0; n < 5; ++n)
                bfr[n] = *(const bf16x8*)(buf + rowB + n * 2048 + klo[kk]);
            __builtin_amdgcn_s_setprio(1);
            #pragma unroll
            for (int m = 0; m < 8; ++m)
                #pragma unroll
                for (int n = 0; n < 5; ++n)
                    acc[m][n] = __builtin_amdgcn_mfma_f32_16x16x32_bf16(
                        af[m], bfr[n], acc[m][n], 0, 0, 0);
            __builtin_amdgcn_s_setprio(0);
        }

        // ---- tile boundary
        asm volatile("s_waitcnt vmcnt(0)" ::: "memory");
        __builtin_amdgcn_s_barrier();
    }

    // ---- epilogue: bias + sigmoid; C/D: col = lane&15, row = (lane>>4)*4+reg
    #pragma unroll
    for (int n = 0; n < 5; ++n) {
        const int col  = bn0 + wc * 80 + n * 16 + llo;
        const float bv = bias[col];
        #pragma unroll
        for (int m = 0; m < 8; ++m) {
            const int row0 = bm0 + wr * 128 + m * 16 + lhi * 4;
            #pragma unroll
            for (int r = 0; r < 4; ++r) {
                const float z = acc[m][n][r] + bv;
                out[(size_t)(row0 + r) * HEADS + col] = __fdividef(1.0f, 1.0f + __expf(-z));
            }
        }
    }
}

// ---------------------------------------------------------------------------
// Fallback (R1 fused kernel) if workspace is too small.
// ---------------------------------------------------------------------------
#define FBM 128
#define FBN 128
#define FBK 32
#define FLDK 40

__global__ __launch_bounds__(256)
void lch_gemm(const float* __restrict__ x, const float* __restrict__ W,
              const float* __restrict__ b, float* __restrict__ out)
{
    __shared__ __bf16 As[FBM][FLDK];
    __shared__ __bf16 Bs[FBN][FLDK];

    const int t   = threadIdx.x;
    const int bm0 = blockIdx.x * FBM;
    const int bn0 = blockIdx.y * FBN;
    const int lane = t & 63;
    const int wid  = t >> 6;
    const int wr   = wid >> 1;
    const int wc   = wid & 1;
    const int lhi  = lane >> 4;
    const int llo  = lane & 15;

    f32x4 acc[4][4];
    #pragma unroll
    for (int i = 0; i < 4; ++i)
        #pragma unroll
        for (int j = 0; j < 4; ++j)
            acc[i][j] = f32x4{0.f, 0.f, 0.f, 0.f};

    const int bn_col  = t & 127;
    const int bk_base = (t >> 7) * 16;

    for (int k0 = 0; k0 < HIDDEN; k0 += FBK) {
        #pragma unroll
        for (int i = 0; i < 4; ++i) {
            const int f   = t + i * 256;
            const int row = f >> 3;
            const int c4  = (f & 7) * 4;
            const float4 v = *reinterpret_cast<const float4*>(
                x + (size_t)(bm0 + row) * HIDDEN + k0 + c4);
            bf16x4 h;
            h[0] = (__bf16)v.x; h[1] = (__bf16)v.y;
            h[2] = (__bf16)v.z; h[3] = (__bf16)v.w;
            *reinterpret_cast<bf16x4*>(&As[row][c4]) = h;
        }
        {
            const float* wp = W + (size_t)(k0 + bk_base) * HEADS + bn0 + bn_col;
            bf16x8 h0, h1;
            #pragma unroll
            for (int i = 0; i < 8; ++i) h0[i] = (__bf16)wp[(size_t)i * HEADS];
            #pragma unroll
            for (int i = 0; i < 8; ++i) h1[i] = (__bf16)wp[(size_t)(i + 8) * HEADS];
            *reinterpret_cast<bf16x8*>(&Bs[bn_col][bk_base])     = h0;
            *reinterpret_cast<bf16x8*>(&Bs[bn_col][bk_base + 8]) = h1;
        }
        __syncthreads();

        bf16x8 af[4], bfr[4];
        #pragma unroll
        for (int i = 0; i < 4; ++i)
            af[i] = *reinterpret_cast<const bf16x8*>(&As[wr * 64 + i * 16 + llo][lhi * 8]);
        #pragma unroll
        for (int j = 0; j < 4; ++j)
            bfr[j] = *reinterpret_cast<const bf16x8*>(&Bs[wc * 64 + j * 16 + llo][lhi * 8]);
        #pragma unroll
        for (int i = 0; i < 4; ++i)
            #pragma unroll
            for (int j = 0; j < 4; ++j)
                acc[i][j] = __builtin_amdgcn_mfma_f32_16x16x32_bf16(
                    af[i], bfr[j], acc[i][j], 0, 0, 0);
        __syncthreads();
    }

    #pragma unroll
    for (int j = 0; j < 4; ++j) {
        const int col  = bn0 + wc * 64 + j * 16 + llo;
        const float bv = b[col];
        #pragma unroll
        for (int i = 0; i < 4; ++i) {
            const int row0 = bm0 + wr * 64 + i * 16 + lhi * 4;
            #pragma unroll
            for (int r = 0; r < 4; ++r) {
                const float z = acc[i][j][r] + bv;
                out[(size_t)(row0 + r) * HEADS + col] = 1.0f / (1.0f + __expf(-z));
            }
        }
    }
}

extern "C" void kernel_launch(void* const* d_in, const int* in_sizes, int n_in,
                              void* d_out, int out_size, void* d_ws, size_t ws_size,
                              hipStream_t stream) {
    const float* x = (const float*)d_in[0];
    const float* W = (const float*)d_in[1];
    const float* b = (const float*)d_in[2];
    float* out     = (float*)d_out;

    const int M = in_sizes[0] / HIDDEN;   // 8192

    const size_t xc_bytes = (size_t)M * HIDDEN * sizeof(__bf16);
    const size_t wt_bytes = (size_t)HEADS * HIDDEN * sizeof(__bf16);

    if (ws_size >= xc_bytes + wt_bytes && (M % BM) == 0) {
        __bf16* xc = (__bf16*)d_ws;
        __bf16* Wt = (__bf16*)((char*)d_ws + xc_bytes);

        cvt_all<<<640 + 2048, 256, 0, stream>>>(x, W, xc, Wt, M * HIDDEN / 8);

        const int nwg = (M / BM) * (HEADS / BN);   // 32 * 8 = 256
        gemm_big<<<nwg, 512, 0, stream>>>(xc, Wt, b, out);
    } else {
        dim3 grid(M / FBM, HEADS / FBN);
        lch_gemm<<<grid, dim3(256), 0, stream>>>(x, W, b, out);
    }
}